// Round 1
// baseline (588.422 us; speedup 1.0000x reference)
//
#include <hip/hip_runtime.h>

typedef float f32x4 __attribute__((ext_vector_type(4)));
typedef short s16x8 __attribute__((ext_vector_type(8)));
typedef int   i32x4 __attribute__((ext_vector_type(4)));

#define BSZ 4
#define SEQ 4096
#define DIM 256
#define NH 10
#define NG 4
#define CHK 1024
#define BS_TOT 16384   // BSZ*SEQ
#define HD 2560        // NH*DIM

__device__ __forceinline__ unsigned short f2bf(float f) {
    unsigned int u = __builtin_bit_cast(unsigned int, f);
    u = (u + 0x7fffu + ((u >> 16) & 1u)) >> 16;
    return (unsigned short)u;
}

// ---------------- cast / transpose helpers ----------------

__global__ __launch_bounds__(256) void cast_f32_bf16(const float* __restrict__ s,
                                                     unsigned short* __restrict__ d, int n) {
    long i = 4L * (blockIdx.x * 256 + threadIdx.x);
    if (i < n) {
        float4 v = *(const float4*)(s + i);
        ushort4 o;
        o.x = f2bf(v.x); o.y = f2bf(v.y); o.z = f2bf(v.z); o.w = f2bf(v.w);
        *(ushort4*)(d + i) = o;
    }
}

// Wt[h][e][d] = W[h][d][e], fp32 -> bf16.  grid (8,8,2*NH), block 256
__global__ __launch_bounds__(256) void transpose_cast_w(const float* __restrict__ Wq,
                                                        const float* __restrict__ Wk,
                                                        unsigned short* __restrict__ wqt,
                                                        unsigned short* __restrict__ wkt) {
    const float* W = (blockIdx.z & 1) ? Wk : Wq;
    unsigned short* Wt = (blockIdx.z & 1) ? wkt : wqt;
    int h = blockIdx.z >> 1;
    __shared__ float tile[32][33];
    int d0 = blockIdx.x * 32, e0 = blockIdx.y * 32;
    int tx = threadIdx.x & 31, ty = threadIdx.x >> 5;
    const float* Wh = W + (long)h * 65536;
    unsigned short* Wth = Wt + (long)h * 65536;
#pragma unroll
    for (int r = ty; r < 32; r += 8) tile[r][tx] = Wh[(long)(d0 + r) * 256 + e0 + tx];
    __syncthreads();
#pragma unroll
    for (int r = ty; r < 32; r += 8) Wth[(long)(e0 + r) * 256 + d0 + tx] = f2bf(tile[tx][r]);
}

// ---------------- generic C[m][n] = sum_k A[m][k] * Bt[n][k], N=256 ----------------
// block 256 thr (4 waves), M-tile 64 (wave w: rows 16w..16w+15)

__device__ __forceinline__ void gemm_body(const unsigned short* __restrict__ A, long lda,
                                          const unsigned short* __restrict__ Bt, long ldb,
                                          unsigned short* Cb, float* Cf, long ldc,
                                          int K, bool accum, long mbase) {
    __shared__ unsigned short As[64 * 40];
    __shared__ unsigned short Bs[256 * 40];
    const int t = threadIdx.x;
    const int w = t >> 6, l = t & 63, lr = l & 15, lg = l >> 4;

    f32x4 acc[16];
#pragma unroll
    for (int i = 0; i < 16; i++) acc[i] = (f32x4){0.f, 0.f, 0.f, 0.f};

    const int ar = t >> 2, akc = (t & 3) * 8;

    for (int k0 = 0; k0 < K; k0 += 32) {
        *(s16x8*)(&As[ar * 40 + akc]) = *(const s16x8*)(A + (mbase + ar) * lda + k0 + akc);
#pragma unroll
        for (int s = 0; s < 4; s++) {
            int n = s * 64 + (t >> 2);
            *(s16x8*)(&Bs[n * 40 + akc]) = *(const s16x8*)(Bt + (long)n * ldb + k0 + akc);
        }
        __syncthreads();
        s16x8 af = *(const s16x8*)(&As[(w * 16 + lr) * 40 + lg * 8]);
#pragma unroll
        for (int nt = 0; nt < 16; nt++) {
            s16x8 bf = *(const s16x8*)(&Bs[(nt * 16 + lr) * 40 + lg * 8]);
            acc[nt] = __builtin_amdgcn_mfma_f32_16x16x32_bf16(af, bf, acc[nt], 0, 0, 0);
        }
        __syncthreads();
    }
    long m0 = mbase + w * 16 + lg * 4;
#pragma unroll
    for (int nt = 0; nt < 16; nt++) {
        int col = nt * 16 + lr;
#pragma unroll
        for (int r = 0; r < 4; r++) {
            long idx = (m0 + r) * ldc + col;
            if (Cb) {
                Cb[idx] = f2bf(acc[nt][r]);
            } else {
                float v = acc[nt][r];
                if (accum) v += Cf[idx];
                Cf[idx] = v;
            }
        }
    }
}

// grid (256, nh, 2)
__global__ __launch_bounds__(256) void proj_kernel(const unsigned short* __restrict__ xb,
                                                   const unsigned short* __restrict__ wqt,
                                                   const unsigned short* __restrict__ wkt,
                                                   unsigned short* Qb, unsigned short* Kb,
                                                   int h0, long headStrideOut) {
    int h = h0 + blockIdx.y;
    const unsigned short* Bt = (blockIdx.z ? wkt : wqt) + (long)h * 65536;
    unsigned short* C = (blockIdx.z ? Kb : Qb) + (long)blockIdx.y * headStrideOut;
    gemm_body(xb, 256, Bt, 256, C, nullptr, 256, 256, false, (long)blockIdx.x * 64);
}

// grid (256,1,1)
__global__ __launch_bounds__(256) void final_kernel(const unsigned short* __restrict__ Ob, long lda,
                                                    const unsigned short* __restrict__ wob, long ldb,
                                                    float* out, int K, int accum) {
    gemm_body(Ob, lda, wob, ldb, nullptr, out, 256, K, accum != 0, (long)blockIdx.x * 64);
}

// ---------------- attention ----------------
// grid (CHK/64=16, BSZ*NG=16, nh), block 256.  wave w: q rows [64*bx + 16w, +16)
// chunk g attends KV chunk (g+1)%4.  V == K.

__global__ __launch_bounds__(256) void attn_kernel(const unsigned short* __restrict__ Qb,
                                                   const unsigned short* __restrict__ Kb,
                                                   long headStrideQK,
                                                   unsigned short* __restrict__ Ob,
                                                   long ldo, long colStride) {
    const int h = blockIdx.z;
    const unsigned short* Q = Qb + (long)h * headStrideQK;
    const unsigned short* Kp = Kb + (long)h * headStrideQK;
    unsigned short* O = Ob + (long)h * colStride;
    const int b = blockIdx.y >> 2, g = blockIdx.y & 3;
    const long qrow0 = (long)b * SEQ + (long)g * CHK + (long)blockIdx.x * 64;
    const long krow0 = (long)b * SEQ + (long)((g + 1) & 3) * CHK;

    __shared__ unsigned short Krm[32 * 264];  // row-major K tile [32 keys][256 d], pad 264
    __shared__ unsigned short Ktr[256 * 40];  // transposed    [256 d][32 keys], pad 40

    const int t = threadIdx.x;
    const int w = t >> 6, l = t & 63, lr = l & 15, lg = l >> 4;

    // Q fragments: lane holds Q[q=lr][d = s*32 + lg*8 + j]
    s16x8 qf[8];
    {
        const unsigned short* qp = Q + (qrow0 + w * 16 + lr) * 256 + lg * 8;
#pragma unroll
        for (int s = 0; s < 8; s++) qf[s] = *(const s16x8*)(qp + s * 32);
    }

    f32x4 o[16];
#pragma unroll
    for (int i = 0; i < 16; i++) o[i] = (f32x4){0.f, 0.f, 0.f, 0.f};
    float m_run = -1e30f, l_part = 0.f;

    for (int kt = 0; kt < 32; ++kt) {
        // stage row-major tile (coalesced 16B)
#pragma unroll
        for (int s = 0; s < 4; s++) {
            int i = s * 256 + t;
            int row = i >> 5, dc = (i & 31) * 8;
            *(s16x8*)(&Krm[row * 264 + dc]) =
                *(const s16x8*)(Kp + (krow0 + kt * 32 + row) * 256 + dc);
        }
        __syncthreads();
        // build transposed tile: thread t owns column d = t
        {
            unsigned int pk[16];
#pragma unroll
            for (int kk = 0; kk < 32; kk += 2) {
                unsigned int a0 = Krm[kk * 264 + t];
                unsigned int a1 = Krm[(kk + 1) * 264 + t];
                pk[kk >> 1] = a0 | (a1 << 16);
            }
#pragma unroll
            for (int c = 0; c < 4; c++) {
                *(i32x4*)(&Ktr[t * 40 + c * 8]) =
                    (i32x4){(int)pk[c * 4], (int)pk[c * 4 + 1], (int)pk[c * 4 + 2], (int)pk[c * 4 + 3]};
            }
        }
        __syncthreads();

        // St = K_tile @ Q^T : lane owns q=lr (col), keys 16*tile + lg*4 + r (rows)
        f32x4 st0 = (f32x4){0.f, 0.f, 0.f, 0.f}, st1 = st0;
#pragma unroll
        for (int s = 0; s < 8; s++) {
            s16x8 a0 = *(const s16x8*)(&Krm[lr * 264 + s * 32 + lg * 8]);
            s16x8 a1 = *(const s16x8*)(&Krm[(16 + lr) * 264 + s * 32 + lg * 8]);
            st0 = __builtin_amdgcn_mfma_f32_16x16x32_bf16(a0, qf[s], st0, 0, 0, 0);
            st1 = __builtin_amdgcn_mfma_f32_16x16x32_bf16(a1, qf[s], st1, 0, 0, 0);
        }

        // online softmax for q = lr
        float vmax = fmaxf(fmaxf(fmaxf(st0[0], st0[1]), fmaxf(st0[2], st0[3])),
                           fmaxf(fmaxf(st1[0], st1[1]), fmaxf(st1[2], st1[3])));
        vmax = fmaxf(vmax, __shfl_xor(vmax, 16));
        vmax = fmaxf(vmax, __shfl_xor(vmax, 32));
        float m_new = fmaxf(m_run, vmax);
        float scale = __expf(m_run - m_new);
        m_run = m_new;
        float p[8];
#pragma unroll
        for (int i = 0; i < 4; i++) {
            p[i] = __expf(st0[i] - m_new);
            p[4 + i] = __expf(st1[i] - m_new);
        }
        float psum = 0.f;
#pragma unroll
        for (int i = 0; i < 8; i++) psum += p[i];
        l_part = l_part * scale + psum;

        // rescale O accumulators (rows q' = lg*4 + r)
        float sc[4];
#pragma unroll
        for (int r = 0; r < 4; r++) sc[r] = __shfl(scale, lg * 4 + r);
#pragma unroll
        for (int nt = 0; nt < 16; nt++) {
            o[nt][0] *= sc[0]; o[nt][1] *= sc[1]; o[nt][2] *= sc[2]; o[nt][3] *= sc[3];
        }

        // pack P -> bf16 pairs; redistribute so lane (lg,lr) holds P[q=lr][key=8*lg+j]
        unsigned int u00 = (unsigned)f2bf(p[0]) | ((unsigned)f2bf(p[1]) << 16);
        unsigned int u01 = (unsigned)f2bf(p[2]) | ((unsigned)f2bf(p[3]) << 16);
        unsigned int u10 = (unsigned)f2bf(p[4]) | ((unsigned)f2bf(p[5]) << 16);
        unsigned int u11 = (unsigned)f2bf(p[6]) | ((unsigned)f2bf(p[7]) << 16);
        int sA = ((2 * lg) & 3) * 16 + lr;
        int sB = ((2 * lg + 1) & 3) * 16 + lr;
        unsigned int w0a = __shfl(u00, sA), w0b = __shfl(u10, sA);
        unsigned int w1a = __shfl(u01, sA), w1b = __shfl(u11, sA);
        unsigned int w2a = __shfl(u00, sB), w2b = __shfl(u10, sB);
        unsigned int w3a = __shfl(u01, sB), w3b = __shfl(u11, sB);
        bool hi = (lg >> 1) != 0;
        i32x4 aw = {(int)(hi ? w0b : w0a), (int)(hi ? w1b : w1a),
                    (int)(hi ? w2b : w2a), (int)(hi ? w3b : w3a)};
        s16x8 pa = __builtin_bit_cast(s16x8, aw);

        // O += P @ V   (V == K, transposed tile)
#pragma unroll
        for (int nt = 0; nt < 16; nt++) {
            s16x8 bv = *(const s16x8*)(&Ktr[(nt * 16 + lr) * 40 + lg * 8]);
            o[nt] = __builtin_amdgcn_mfma_f32_16x16x32_bf16(pa, bv, o[nt], 0, 0, 0);
        }
        __syncthreads();
    }

    // epilogue: divide by l, store bf16
    float lt = l_part + __shfl_xor(l_part, 16);
    lt += __shfl_xor(lt, 32);
    float rinv = 1.0f / lt;
    float ri[4];
#pragma unroll
    for (int r = 0; r < 4; r++) ri[r] = __shfl(rinv, lg * 4 + r);
    long orow0 = qrow0 + w * 16 + lg * 4;
#pragma unroll
    for (int nt = 0; nt < 16; nt++) {
#pragma unroll
        for (int r = 0; r < 4; r++) {
            O[(orow0 + r) * ldo + nt * 16 + lr] = f2bf(o[nt][r] * ri[r]);
        }
    }
}

// ---------------- host ----------------

extern "C" void kernel_launch(void* const* d_in, const int* in_sizes, int n_in,
                              void* d_out, int out_size, void* d_ws, size_t ws_size,
                              hipStream_t stream) {
    const float* x  = (const float*)d_in[0];
    const float* Wq = (const float*)d_in[1];
    const float* Wk = (const float*)d_in[2];
    const float* Wo = (const float*)d_in[3];
    float* out = (float*)d_out;
    char* ws = (char*)d_ws;

    unsigned short* xb  = (unsigned short*)(ws);
    unsigned short* wqt = (unsigned short*)(ws + 8388608);
    unsigned short* wkt = (unsigned short*)(ws + 9699328);
    unsigned short* wob = (unsigned short*)(ws + 11010048);
    char* dyn = ws + 12320768;

    cast_f32_bf16<<<4096, 256, 0, stream>>>(x, xb, BS_TOT * DIM);
    cast_f32_bf16<<<640, 256, 0, stream>>>(Wo, wob, DIM * HD);
    transpose_cast_w<<<dim3(8, 8, 2 * NH), 256, 0, stream>>>(Wq, Wk, wqt, wkt);

    const size_t FULL_NEED = 12320768ULL + 3ULL * 83886080ULL;   // ~264 MB
    const long perHeadElems = (long)BS_TOT * DIM;                // 4,194,304

    if (ws_size >= FULL_NEED) {
        unsigned short* Qb = (unsigned short*)dyn;
        unsigned short* Kb = Qb + (long)NH * perHeadElems;
        unsigned short* Ob = Kb + (long)NH * perHeadElems;
        proj_kernel<<<dim3(256, NH, 2), 256, 0, stream>>>(xb, wqt, wkt, Qb, Kb, 0, perHeadElems);
        attn_kernel<<<dim3(16, 16, NH), 256, 0, stream>>>(Qb, Kb, perHeadElems, Ob, HD, 256);
        final_kernel<<<dim3(256, 1, 1), 256, 0, stream>>>(Ob, HD, wob, HD, out, HD, 0);
    } else {
        unsigned short* Qh = (unsigned short*)dyn;
        unsigned short* Kh = Qh + perHeadElems;
        unsigned short* Oh = Kh + perHeadElems;
        hipMemsetAsync(d_out, 0, (size_t)out_size * 4, stream);
        for (int h = 0; h < NH; ++h) {
            proj_kernel<<<dim3(256, 1, 2), 256, 0, stream>>>(xb, wqt, wkt, Qh, Kh, h, 0);
            attn_kernel<<<dim3(16, 16, 1), 256, 0, stream>>>(Qh, Kh, 0, Oh, 256, 0);
            final_kernel<<<dim3(256, 1, 1), 256, 0, stream>>>(Oh, 256, wob + h * 256, HD, out, 256, 1);
        }
    }
}